// Round 5
// baseline (114.391 us; speedup 1.0000x reference)
//
#include <hip/hip_runtime.h>
#include <hip/hip_bf16.h>

#define BB 16
#define FF 128
#define HH 144
#define EE 24
#define C0C 12
#define FP1 (FF + 1)   // 129

typedef float v4f __attribute__((ext_vector_type(4)));

// Workspace layout (floats), h-major so K1 writes are coalesced:
//   num_t: [B][H][F+1]  (cumsum of p*d, leading zero at col 0)
//   den_t: [B][H][F+1]  (cumsum of p,   leading zero at col 0)
#define TABLE_ELEMS (BB * HH * FP1)

__device__ __forceinline__ float fastdiv(float n, float d) {
    float r = __builtin_amdgcn_rcpf(d);
    r = fmaf(fmaf(-d, r, 1.0f), r, r);   // one Newton iteration
    return n * r;
}

__global__ __launch_bounds__(128) void seg_k1(
    const float* __restrict__ note,   // [B][F][E]
    const float* __restrict__ hv,     // [B][H][E]
    const float* __restrict__ W0,     // [12][12]
    const float* __restrict__ b0,     // [12]
    const float* __restrict__ W1,     // [12][12]
    const float* __restrict__ b1,     // [12]
    const float* __restrict__ Wc,     // [24][24]
    const float* __restrict__ bc,     // [24]
    float* __restrict__ num_t,
    float* __restrict__ den_t)
{
    const int blk = blockIdx.x;           // b*H + h
    const int b = blk / HH;
    const int h = blk - b * HH;
    const int tid = threadIdx.x;
    const int lane = tid & 63;

    __shared__ float s_hcat[EE];
    __shared__ float s_q[EE];
    __shared__ float s_wmax[2];
    __shared__ float s_tot[2];

    const float* hvb = hv + ((size_t)b * HH + h) * EE;
    if (tid < C0C) {
        float acc = b0[tid];
        #pragma unroll
        for (int j = 0; j < C0C; ++j) acc += W0[tid * C0C + j] * hvb[j];
        s_hcat[tid] = acc;
    } else if (tid < 2 * C0C) {
        const int i = tid - C0C;
        float acc = b1[i];
        #pragma unroll
        for (int j = 0; j < C0C; ++j) acc += W1[i * C0C + j] * hvb[C0C + j];
        s_hcat[tid] = acc;
    }
    __syncthreads();
    if (tid < EE) {
        float acc = bc[tid];
        #pragma unroll
        for (int j = 0; j < EE; ++j) acc += Wc[tid * EE + j] * s_hcat[j];
        s_q[tid] = acc;
    }
    __syncthreads();

    // d_l for l = tid, note row read straight from global (L2-resident)
    const float* nr = note + ((size_t)b * FF + tid) * EE;
    float d = 0.f;
    #pragma unroll
    for (int e = 0; e < EE; e += 4) {
        const v4f v = *reinterpret_cast<const v4f*>(nr + e);
        d += s_q[e] * v.x + s_q[e + 1] * v.y + s_q[e + 2] * v.z + s_q[e + 3] * v.w;
    }

    const float scale = 0.20412414523193150818f;  // 1/sqrt(24)
    const float ds = d * scale;

    // block max over 128 threads (2 waves)
    float m = ds;
    #pragma unroll
    for (int off = 32; off > 0; off >>= 1) m = fmaxf(m, __shfl_xor(m, off));
    if (lane == 0) s_wmax[tid >> 6] = m;
    __syncthreads();
    m = fmaxf(s_wmax[0], s_wmax[1]);

    float p = __expf(ds - m);
    float pd = p * d;

    // in-wave inclusive scan (width 64), then cross-wave fixup
    #pragma unroll
    for (int off = 1; off < 64; off <<= 1) {
        const float a = __shfl_up(p, off);
        const float c = __shfl_up(pd, off);
        if (lane >= off) { p += a; pd += c; }
    }
    if (tid == 63) { s_tot[0] = p; s_tot[1] = pd; }
    __syncthreads();
    if (tid >= 64) { p += s_tot[0]; pd += s_tot[1]; }

    // coalesced: lanes write consecutive columns of row (b,h)
    const size_t base = ((size_t)b * HH + h) * FP1;
    num_t[base + tid + 1] = pd;
    den_t[base + tid + 1] = p;
    if (tid == 0) {
        num_t[base] = 0.f;
        den_t[base] = 0.f;
    }
}

__global__ __launch_bounds__(256) void seg_k2(
    const float* __restrict__ num_t,
    const float* __restrict__ den_t,
    float* __restrict__ out)          // [B][F(s)][F(e)][H]
{
    const int blk = blockIdx.x;        // b*F + s
    const int b = blk >> 7;
    const int s = blk & 127;
    const int tid = threadIdx.x;

    const float* nb = num_t + (size_t)b * HH * FP1;
    const float* db = den_t + (size_t)b * HH * FP1;
    float* ob = out + (size_t)blk * (FF * HH);

    // ---- Phase A: rows e in [0, s) are zero. Pure coalesced stores. ----
    const int nz4 = s * (HH / 4);                 // float4 chunks to zero
    for (int c = tid; c < nz4; c += 256) {
        *reinterpret_cast<v4f*>(ob + (size_t)c * 4) = (v4f)(0.f);
    }

    // ---- Phase B: rows e in [s, 128). tid -> (r, hq), fixed h = 4*hq. ----
    if (tid < 252) {
        const int r = tid / 36;                   // 0..6  (row offset)
        const int hq = tid - r * 36;              // 0..35 (16B chunk in row)
        const int h = hq * 4;

        const float* pn = nb + (size_t)h * FP1;   // rows h..h+3, stride FP1
        const float* pdn = db + (size_t)h * FP1;

        v4f n0, d0;
        n0.x = pn[s];            n0.y = pn[FP1 + s];
        n0.z = pn[2 * FP1 + s];  n0.w = pn[3 * FP1 + s];
        d0.x = pdn[s];           d0.y = pdn[FP1 + s];
        d0.z = pdn[2 * FP1 + s]; d0.w = pdn[3 * FP1 + s];

        #pragma unroll 2
        for (int e = s + r; e < FF; e += 7) {
            const int c = e + 1;
            v4f n1, d1;
            n1.x = pn[c];            n1.y = pn[FP1 + c];
            n1.z = pn[2 * FP1 + c];  n1.w = pn[3 * FP1 + c];
            d1.x = pdn[c];           d1.y = pdn[FP1 + c];
            d1.z = pdn[2 * FP1 + c]; d1.w = pdn[3 * FP1 + c];
            v4f val;
            val.x = fastdiv(n1.x - n0.x, d1.x - d0.x);
            val.y = fastdiv(n1.y - n0.y, d1.y - d0.y);
            val.z = fastdiv(n1.z - n0.z, d1.z - d0.z);
            val.w = fastdiv(n1.w - n0.w, d1.w - d0.w);
            *reinterpret_cast<v4f*>(ob + (size_t)e * HH + h) = val;
        }
    }
}

extern "C" void kernel_launch(void* const* d_in, const int* in_sizes, int n_in,
                              void* d_out, int out_size, void* d_ws, size_t ws_size,
                              hipStream_t stream) {
    const float* note = (const float*)d_in[0];
    const float* hv   = (const float*)d_in[1];
    const float* W0   = (const float*)d_in[2];
    const float* b0   = (const float*)d_in[3];
    const float* W1   = (const float*)d_in[4];
    const float* b1   = (const float*)d_in[5];
    const float* Wc   = (const float*)d_in[6];
    const float* bc   = (const float*)d_in[7];
    float* out = (float*)d_out;

    float* num_t = (float*)d_ws;
    float* den_t = num_t + TABLE_ELEMS;

    seg_k1<<<BB * HH, 128, 0, stream>>>(note, hv, W0, b0, W1, b1, Wc, bc, num_t, den_t);
    seg_k2<<<BB * FF, 256, 0, stream>>>(num_t, den_t, out);
}

// Round 6
// 39.626 us; speedup vs baseline: 2.8867x; 2.8867x over previous
//
#include <hip/hip_runtime.h>
#include <hip/hip_bf16.h>

#define BB 16
#define FF 128
#define HH 144
#define EE 24
#define C0C 12

typedef float v4f __attribute__((ext_vector_type(4)));

// Workspace layout (floats), h-minor so K2 reads are lane-coalesced:
//   num_t: [B][F+1][H]  (cumsum of p*d, leading zero row)
//   den_t: [B][F+1][H]  (cumsum of p,   leading zero row)
#define TABLE_ELEMS (BB * (FF + 1) * HH)

__device__ __forceinline__ float fastdiv(float n, float d) {
    float r = __builtin_amdgcn_rcpf(d);
    r = fmaf(fmaf(-d, r, 1.0f), r, r);   // one Newton iteration
    return n * r;
}

__global__ __launch_bounds__(128) void seg_k1(
    const float* __restrict__ note,   // [B][F][E]
    const float* __restrict__ hv,     // [B][H][E]
    const float* __restrict__ W0,     // [12][12]
    const float* __restrict__ b0,     // [12]
    const float* __restrict__ W1,     // [12][12]
    const float* __restrict__ b1,     // [12]
    const float* __restrict__ Wc,     // [24][24]
    const float* __restrict__ bc,     // [24]
    float* __restrict__ num_t,
    float* __restrict__ den_t)
{
    const int blk = blockIdx.x;           // b*H + h
    const int b = blk / HH;
    const int h = blk - b * HH;
    const int tid = threadIdx.x;
    const int lane = tid & 63;

    __shared__ float s_hcat[EE];
    __shared__ float s_q[EE];
    __shared__ float s_wmax[2];
    __shared__ float s_tot[2];

    const float* hvb = hv + ((size_t)b * HH + h) * EE;
    if (tid < C0C) {
        float acc = b0[tid];
        #pragma unroll
        for (int j = 0; j < C0C; ++j) acc += W0[tid * C0C + j] * hvb[j];
        s_hcat[tid] = acc;
    } else if (tid < 2 * C0C) {
        const int i = tid - C0C;
        float acc = b1[i];
        #pragma unroll
        for (int j = 0; j < C0C; ++j) acc += W1[i * C0C + j] * hvb[C0C + j];
        s_hcat[tid] = acc;
    }
    __syncthreads();
    if (tid < EE) {
        float acc = bc[tid];
        #pragma unroll
        for (int j = 0; j < EE; ++j) acc += Wc[tid * EE + j] * s_hcat[j];
        s_q[tid] = acc;
    }
    __syncthreads();

    // d_l for l = tid, note row read straight from global (L2-resident)
    const float* nr = note + ((size_t)b * FF + tid) * EE;
    float d = 0.f;
    #pragma unroll
    for (int e = 0; e < EE; e += 4) {
        const v4f v = *reinterpret_cast<const v4f*>(nr + e);
        d += s_q[e] * v.x + s_q[e + 1] * v.y + s_q[e + 2] * v.z + s_q[e + 3] * v.w;
    }

    const float scale = 0.20412414523193150818f;  // 1/sqrt(24)
    const float ds = d * scale;

    // block max over 128 threads (2 waves)
    float m = ds;
    #pragma unroll
    for (int off = 32; off > 0; off >>= 1) m = fmaxf(m, __shfl_xor(m, off));
    if (lane == 0) s_wmax[tid >> 6] = m;
    __syncthreads();
    m = fmaxf(s_wmax[0], s_wmax[1]);

    float p = __expf(ds - m);
    float pd = p * d;

    // in-wave inclusive scan (width 64), then cross-wave fixup
    #pragma unroll
    for (int off = 1; off < 64; off <<= 1) {
        const float a = __shfl_up(p, off);
        const float c = __shfl_up(pd, off);
        if (lane >= off) { p += a; pd += c; }
    }
    if (tid == 63) { s_tot[0] = p; s_tot[1] = pd; }
    __syncthreads();
    if (tid >= 64) { p += s_tot[0]; pd += s_tot[1]; }

    const size_t base = (size_t)b * (FF + 1) * HH + h;
    num_t[base + (size_t)(tid + 1) * HH] = pd;
    den_t[base + (size_t)(tid + 1) * HH] = p;
    if (tid == 0) {
        num_t[base] = 0.f;
        den_t[base] = 0.f;
    }
}

__device__ __forceinline__ void k2_row(
    const float* __restrict__ nb, const float* __restrict__ db,
    float* __restrict__ out_b, int s, int tid)
{
    float* ob = out_b + (size_t)s * (FF * HH);

    // ---- Phase A: rows e in [0, s) are zero. Pure coalesced stores. ----
    const int nz4 = s * (HH / 4);                 // float4 chunks to zero
    for (int c = tid; c < nz4; c += 256) {
        *reinterpret_cast<v4f*>(ob + (size_t)c * 4) = (v4f)(0.f);
    }

    // ---- Phase B: rows e in [s, 128). tid -> (r, hq), fixed h = 4*hq. ----
    if (tid < 252) {
        const int r = tid / 36;                   // 0..6  (row offset)
        const int hq = tid - r * 36;              // 0..35 (16B chunk in row)
        const int h = hq * 4;

        const v4f n0 = *reinterpret_cast<const v4f*>(nb + (size_t)s * HH + h);
        const v4f d0 = *reinterpret_cast<const v4f*>(db + (size_t)s * HH + h);

        const float* pn = nb + (size_t)(s + r + 1) * HH + h;
        const float* pd_ = db + (size_t)(s + r + 1) * HH + h;
        float* po = ob + (size_t)(s + r) * HH + h;

        #pragma unroll 2
        for (int e = s + r; e < FF; e += 7) {
            const v4f n1 = *reinterpret_cast<const v4f*>(pn);
            const v4f d1 = *reinterpret_cast<const v4f*>(pd_);
            v4f val;
            val.x = fastdiv(n1.x - n0.x, d1.x - d0.x);
            val.y = fastdiv(n1.y - n0.y, d1.y - d0.y);
            val.z = fastdiv(n1.z - n0.z, d1.z - d0.z);
            val.w = fastdiv(n1.w - n0.w, d1.w - d0.w);
            *reinterpret_cast<v4f*>(po) = val;
            pn += 7 * HH;
            pd_ += 7 * HH;
            po += 7 * HH;
        }
    }
}

__global__ __launch_bounds__(256) void seg_k2(
    const float* __restrict__ num_t,
    const float* __restrict__ den_t,
    float* __restrict__ out)          // [B][F(s)][F(e)][H]
{
    const int blk = blockIdx.x;        // b*64 + sp ; handles s=sp and s=127-sp
    const int b = blk >> 6;
    const int sp = blk & 63;
    const int tid = threadIdx.x;

    const float* nb = num_t + (size_t)b * (FF + 1) * HH;
    const float* db = den_t + (size_t)b * (FF + 1) * HH;
    float* out_b = out + (size_t)b * (FF * FF * HH);

    // paired s values: total work (zero rows + compute rows) is constant
    k2_row(nb, db, out_b, sp, tid);
    k2_row(nb, db, out_b, 127 - sp, tid);
}

extern "C" void kernel_launch(void* const* d_in, const int* in_sizes, int n_in,
                              void* d_out, int out_size, void* d_ws, size_t ws_size,
                              hipStream_t stream) {
    const float* note = (const float*)d_in[0];
    const float* hv   = (const float*)d_in[1];
    const float* W0   = (const float*)d_in[2];
    const float* b0   = (const float*)d_in[3];
    const float* W1   = (const float*)d_in[4];
    const float* b1   = (const float*)d_in[5];
    const float* Wc   = (const float*)d_in[6];
    const float* bc   = (const float*)d_in[7];
    float* out = (float*)d_out;

    float* num_t = (float*)d_ws;
    float* den_t = num_t + TABLE_ELEMS;

    seg_k1<<<BB * HH, 128, 0, stream>>>(note, hv, W0, b0, W1, b1, Wc, bc, num_t, den_t);
    seg_k2<<<BB * 64, 256, 0, stream>>>(num_t, den_t, out);
}

// Round 7
// 38.316 us; speedup vs baseline: 2.9855x; 1.0342x over previous
//
#include <hip/hip_runtime.h>
#include <hip/hip_bf16.h>

#define BB 16
#define FF 128
#define HH 144
#define EE 24
#define C0C 12

typedef float v4f __attribute__((ext_vector_type(4)));

// Workspace layout (floats), h-minor so K2 reads are lane-coalesced:
//   num_t: [B][F+1][H]  (cumsum of p*d, leading zero row)
//   den_t: [B][F+1][H]  (cumsum of p,   leading zero row)
#define TABLE_ELEMS (BB * (FF + 1) * HH)

__device__ __forceinline__ float fastdiv(float n, float d) {
    float r = __builtin_amdgcn_rcpf(d);
    r = fmaf(fmaf(-d, r, 1.0f), r, r);   // one Newton iteration
    return n * r;
}

__global__ __launch_bounds__(128) void seg_k1(
    const float* __restrict__ note,   // [B][F][E]
    const float* __restrict__ hv,     // [B][H][E]
    const float* __restrict__ W0,     // [12][12]
    const float* __restrict__ b0,     // [12]
    const float* __restrict__ W1,     // [12][12]
    const float* __restrict__ b1,     // [12]
    const float* __restrict__ Wc,     // [24][24]
    const float* __restrict__ bc,     // [24]
    float* __restrict__ num_t,
    float* __restrict__ den_t)
{
    const int blk = blockIdx.x;           // b*H + h
    const int b = blk / HH;
    const int h = blk - b * HH;
    const int tid = threadIdx.x;
    const int lane = tid & 63;

    __shared__ float s_hcat[EE];
    __shared__ float s_q[EE];
    __shared__ float s_wmax[2];
    __shared__ float s_tot[2];

    const float* hvb = hv + ((size_t)b * HH + h) * EE;
    if (tid < C0C) {
        float acc = b0[tid];
        #pragma unroll
        for (int j = 0; j < C0C; ++j) acc += W0[tid * C0C + j] * hvb[j];
        s_hcat[tid] = acc;
    } else if (tid < 2 * C0C) {
        const int i = tid - C0C;
        float acc = b1[i];
        #pragma unroll
        for (int j = 0; j < C0C; ++j) acc += W1[i * C0C + j] * hvb[C0C + j];
        s_hcat[tid] = acc;
    }
    __syncthreads();
    if (tid < EE) {
        float acc = bc[tid];
        #pragma unroll
        for (int j = 0; j < EE; ++j) acc += Wc[tid * EE + j] * s_hcat[j];
        s_q[tid] = acc;
    }
    __syncthreads();

    // d_l for l = tid, note row read straight from global (L2-resident)
    const float* nr = note + ((size_t)b * FF + tid) * EE;
    float d = 0.f;
    #pragma unroll
    for (int e = 0; e < EE; e += 4) {
        const v4f v = *reinterpret_cast<const v4f*>(nr + e);
        d += s_q[e] * v.x + s_q[e + 1] * v.y + s_q[e + 2] * v.z + s_q[e + 3] * v.w;
    }

    const float scale = 0.20412414523193150818f;  // 1/sqrt(24)
    const float ds = d * scale;

    // block max over 128 threads (2 waves)
    float m = ds;
    #pragma unroll
    for (int off = 32; off > 0; off >>= 1) m = fmaxf(m, __shfl_xor(m, off));
    if (lane == 0) s_wmax[tid >> 6] = m;
    __syncthreads();
    m = fmaxf(s_wmax[0], s_wmax[1]);

    float p = __expf(ds - m);
    float pd = p * d;

    // in-wave inclusive scan (width 64), then cross-wave fixup
    #pragma unroll
    for (int off = 1; off < 64; off <<= 1) {
        const float a = __shfl_up(p, off);
        const float c = __shfl_up(pd, off);
        if (lane >= off) { p += a; pd += c; }
    }
    if (tid == 63) { s_tot[0] = p; s_tot[1] = pd; }
    __syncthreads();
    if (tid >= 64) { p += s_tot[0]; pd += s_tot[1]; }

    const size_t base = (size_t)b * (FF + 1) * HH + h;
    num_t[base + (size_t)(tid + 1) * HH] = pd;
    den_t[base + (size_t)(tid + 1) * HH] = p;
    if (tid == 0) {
        num_t[base] = 0.f;
        den_t[base] = 0.f;
    }
}

// Process the (b,s) output slab, but only the rows assigned to `half`:
//   zero rows: row ≡ half (mod 2), row < s
//   compute rows: e = s + r + 7*half + 14k  (r = tid/36)
__device__ __forceinline__ void k2_row_half(
    const float* __restrict__ nb, const float* __restrict__ db,
    float* __restrict__ out_b, int s, int tid, int half)
{
    float* ob = out_b + (size_t)s * (FF * HH);

    // ---- Phase A: zero rows of parity `half` below s ----
    const int nzr = (s - half + 1) >> 1;          // count of such rows
    for (int c = tid; c < nzr * 36; c += 256) {
        const int row2 = c / 36;
        const int col = c - row2 * 36;
        const int row = 2 * row2 + half;
        *reinterpret_cast<v4f*>(ob + (size_t)row * HH + col * 4) = (v4f)(0.f);
    }

    // ---- Phase B: compute rows ----
    if (tid < 252) {
        const int r = tid / 36;                   // 0..6
        const int hq = tid - r * 36;              // 0..35
        const int h = hq * 4;

        const v4f n0 = *reinterpret_cast<const v4f*>(nb + (size_t)s * HH + h);
        const v4f d0 = *reinterpret_cast<const v4f*>(db + (size_t)s * HH + h);

        const int e0 = s + r + 7 * half;
        const float* pn = nb + (size_t)(e0 + 1) * HH + h;
        const float* pd_ = db + (size_t)(e0 + 1) * HH + h;
        float* po = ob + (size_t)e0 * HH + h;

        #pragma unroll 2
        for (int e = e0; e < FF; e += 14) {
            const v4f n1 = *reinterpret_cast<const v4f*>(pn);
            const v4f d1 = *reinterpret_cast<const v4f*>(pd_);
            v4f val;
            val.x = fastdiv(n1.x - n0.x, d1.x - d0.x);
            val.y = fastdiv(n1.y - n0.y, d1.y - d0.y);
            val.z = fastdiv(n1.z - n0.z, d1.z - d0.z);
            val.w = fastdiv(n1.w - n0.w, d1.w - d0.w);
            *reinterpret_cast<v4f*>(po) = val;
            pn += 14 * HH;
            pd_ += 14 * HH;
            po += 14 * HH;
        }
    }
}

__global__ __launch_bounds__(256) void seg_k2(
    const float* __restrict__ num_t,
    const float* __restrict__ den_t,
    float* __restrict__ out)          // [B][F(s)][F(e)][H]
{
    const int blk = blockIdx.x;        // b*128 + sp*2 + half
    const int b = blk >> 7;
    const int rest = blk & 127;
    const int sp = rest >> 1;          // 0..63
    const int half = rest & 1;
    const int tid = threadIdx.x;

    const float* nb = num_t + (size_t)b * (FF + 1) * HH;
    const float* db = den_t + (size_t)b * (FF + 1) * HH;
    float* out_b = out + (size_t)b * (FF * FF * HH);

    // paired s values: total work per block is constant across the grid
    k2_row_half(nb, db, out_b, sp, tid, half);
    k2_row_half(nb, db, out_b, 127 - sp, tid, half);
}

extern "C" void kernel_launch(void* const* d_in, const int* in_sizes, int n_in,
                              void* d_out, int out_size, void* d_ws, size_t ws_size,
                              hipStream_t stream) {
    const float* note = (const float*)d_in[0];
    const float* hv   = (const float*)d_in[1];
    const float* W0   = (const float*)d_in[2];
    const float* b0   = (const float*)d_in[3];
    const float* W1   = (const float*)d_in[4];
    const float* b1   = (const float*)d_in[5];
    const float* Wc   = (const float*)d_in[6];
    const float* bc   = (const float*)d_in[7];
    float* out = (float*)d_out;

    float* num_t = (float*)d_ws;
    float* den_t = num_t + TABLE_ELEMS;

    seg_k1<<<BB * HH, 128, 0, stream>>>(note, hv, W0, b0, W1, b1, Wc, bc, num_t, den_t);
    seg_k2<<<BB * FF, 256, 0, stream>>>(num_t, den_t, out);
}

// Round 8
// 36.580 us; speedup vs baseline: 3.1271x; 1.0475x over previous
//
#include <hip/hip_runtime.h>
#include <hip/hip_bf16.h>

#define BB 16
#define FF 128
#define HH 144
#define EE 24
#define C0C 12

typedef float v4f __attribute__((ext_vector_type(4)));

// Workspace layout (floats), h-minor so K2 reads are lane-coalesced:
//   num_t: [B][F+1][H]  (cumsum of p*d, leading zero row)
//   den_t: [B][F+1][H]  (cumsum of p,   leading zero row)
#define TABLE_ELEMS (BB * (FF + 1) * HH)

__device__ __forceinline__ float fastdiv(float n, float d) {
    float r = __builtin_amdgcn_rcpf(d);
    r = fmaf(fmaf(-d, r, 1.0f), r, r);   // one Newton iteration
    return n * r;
}

// One block per (b, 16-wide h-tile). 144 blocks, 256 threads.
// Computes q, d, softmax terms and the f-scan for 16 h columns in LDS,
// then writes the tables as full 64B-line segments (16 h * 4B, aligned).
// Block->b mapping matches K2's XCD swizzle: xcd = blk&7 owns b = 2*xcd(+1).
__global__ __launch_bounds__(256) void seg_k1(
    const float* __restrict__ note,   // [B][F][E]
    const float* __restrict__ hv,     // [B][H][E]
    const float* __restrict__ W0,     // [12][12]
    const float* __restrict__ b0,     // [12]
    const float* __restrict__ W1,     // [12][12]
    const float* __restrict__ b1,     // [12]
    const float* __restrict__ Wc,     // [24][24]
    const float* __restrict__ bc,     // [24]
    float* __restrict__ num_t,
    float* __restrict__ den_t)
{
    const int blk = blockIdx.x;        // 144 = 8 xcd * 18
    const int x = blk & 7;
    const int t = blk >> 3;            // 0..17
    const int b = 2 * x + (t >= 9);
    const int tile = (t >= 9) ? t - 9 : t;   // 0..8
    const int h0 = tile * 16;
    const int tid = threadIdx.x;

    __shared__ float s_note[FF * EE];  // 12 KB
    __shared__ float s_hcat[16][EE];
    __shared__ float s_q[16][EE];
    __shared__ float s_p[FF][16];      // 8 KB
    __shared__ float s_pd[FF][16];     // 8 KB
    __shared__ float s_pm[16][16];
    __shared__ float s_m[16];

    // stage note[b] coalesced (768 v4f / 256 thr = 3 each)
    const float* nb_ = note + (size_t)b * FF * EE;
    for (int k = tid; k < FF * EE / 4; k += 256)
        reinterpret_cast<v4f*>(s_note)[k] = reinterpret_cast<const v4f*>(nb_)[k];

    // hcat for the 16 harmonies of this tile
    for (int idx = tid; idx < 16 * EE; idx += 256) {
        const int hl = idx / EE, e = idx - hl * EE;
        const float* hvb = hv + ((size_t)b * HH + h0 + hl) * EE;
        float acc;
        if (e < C0C) {
            acc = b0[e];
            #pragma unroll
            for (int j = 0; j < C0C; ++j) acc += W0[e * C0C + j] * hvb[j];
        } else {
            const int e1 = e - C0C;
            acc = b1[e1];
            #pragma unroll
            for (int j = 0; j < C0C; ++j) acc += W1[e1 * C0C + j] * hvb[C0C + j];
        }
        s_hcat[hl][e] = acc;
    }
    __syncthreads();
    for (int idx = tid; idx < 16 * EE; idx += 256) {
        const int hl = idx / EE, e = idx - hl * EE;
        float acc = bc[e];
        #pragma unroll
        for (int j = 0; j < EE; ++j) acc += Wc[e * EE + j] * s_hcat[hl][j];
        s_q[hl][e] = acc;
    }
    __syncthreads();

    // d for 8 f's per thread; thread = (hl = tid&15, f0 = tid>>4)
    const int hl = tid & 15;
    const int f0 = tid >> 4;
    const float scale = 0.20412414523193150818f;  // 1/sqrt(24)

    float dv[8];
    float pmax = -3.4e38f;
    #pragma unroll
    for (int k = 0; k < 8; ++k) {
        const int f = f0 + (k << 4);
        float acc = 0.f;
        #pragma unroll
        for (int e = 0; e < EE; ++e) acc += s_q[hl][e] * s_note[f * EE + e];
        dv[k] = acc;
        pmax = fmaxf(pmax, acc);
    }
    s_pm[f0][hl] = pmax * scale;   // column-partial max of d*scale (scale > 0)
    __syncthreads();
    if (tid < 16) {
        float m = s_pm[0][tid];
        #pragma unroll
        for (int r = 1; r < 16; ++r) m = fmaxf(m, s_pm[r][tid]);
        s_m[tid] = m;
    }
    __syncthreads();
    const float m = s_m[hl];

    #pragma unroll
    for (int k = 0; k < 8; ++k) {
        const int f = f0 + (k << 4);
        const float p = __expf(dv[k] * scale - m);
        s_p[f][hl] = p;
        s_pd[f][hl] = p * dv[k];
    }
    __syncthreads();

    // Hillis-Steele inclusive scan over f (16 columns in parallel)
    for (int off = 1; off < FF; off <<= 1) {
        float tp[8], tpd[8];
        #pragma unroll
        for (int k = 0; k < 8; ++k) {
            const int f = f0 + (k << 4);
            tp[k] = (f >= off) ? s_p[f - off][hl] : 0.f;
            tpd[k] = (f >= off) ? s_pd[f - off][hl] : 0.f;
        }
        __syncthreads();
        #pragma unroll
        for (int k = 0; k < 8; ++k) {
            const int f = f0 + (k << 4);
            if (f >= off) { s_p[f][hl] += tp[k]; s_pd[f][hl] += tpd[k]; }
        }
        __syncthreads();
    }

    // write tables: full 64B segments per f-row
    const size_t base = (size_t)b * (FF + 1) * HH + h0;
    for (int idx4 = tid; idx4 < 512; idx4 += 256) {
        const int f = idx4 >> 2;           // 0..127
        const int hh = (idx4 & 3) * 4;     // 0,4,8,12
        *reinterpret_cast<v4f*>(num_t + base + (size_t)(f + 1) * HH + hh) =
            *reinterpret_cast<const v4f*>(&s_pd[f][hh]);
        *reinterpret_cast<v4f*>(den_t + base + (size_t)(f + 1) * HH + hh) =
            *reinterpret_cast<const v4f*>(&s_p[f][hh]);
    }
    if (tid < 16) {
        num_t[base + tid] = 0.f;
        den_t[base + tid] = 0.f;
    }
}

// Process the (b,s) output slab, rows assigned to `half`:
//   zero rows: row ≡ half (mod 2), row < s
//   compute rows: e = s + r + 7*half + 14k  (r = tid/36)
__device__ __forceinline__ void k2_row_half(
    const float* __restrict__ nb, const float* __restrict__ db,
    float* __restrict__ out_b, int s, int tid, int half)
{
    float* ob = out_b + (size_t)s * (FF * HH);

    // ---- Phase A: zero rows of parity `half` below s ----
    const int nzr = (s - half + 1) >> 1;          // count of such rows
    for (int c = tid; c < nzr * 36; c += 256) {
        const int row2 = c / 36;
        const int col = c - row2 * 36;
        const int row = 2 * row2 + half;
        *reinterpret_cast<v4f*>(ob + (size_t)row * HH + col * 4) = (v4f)(0.f);
    }

    // ---- Phase B: compute rows ----
    if (tid < 252) {
        const int r = tid / 36;                   // 0..6
        const int hq = tid - r * 36;              // 0..35
        const int h = hq * 4;

        const v4f n0 = *reinterpret_cast<const v4f*>(nb + (size_t)s * HH + h);
        const v4f d0 = *reinterpret_cast<const v4f*>(db + (size_t)s * HH + h);

        const int e0 = s + r + 7 * half;
        const float* pn = nb + (size_t)(e0 + 1) * HH + h;
        const float* pd_ = db + (size_t)(e0 + 1) * HH + h;
        float* po = ob + (size_t)e0 * HH + h;

        #pragma unroll 2
        for (int e = e0; e < FF; e += 14) {
            const v4f n1 = *reinterpret_cast<const v4f*>(pn);
            const v4f d1 = *reinterpret_cast<const v4f*>(pd_);
            v4f val;
            val.x = fastdiv(n1.x - n0.x, d1.x - d0.x);
            val.y = fastdiv(n1.y - n0.y, d1.y - d0.y);
            val.z = fastdiv(n1.z - n0.z, d1.z - d0.z);
            val.w = fastdiv(n1.w - n0.w, d1.w - d0.w);
            *reinterpret_cast<v4f*>(po) = val;
            pn += 14 * HH;
            pd_ += 14 * HH;
            po += 14 * HH;
        }
    }
}

__global__ __launch_bounds__(256) void seg_k2(
    const float* __restrict__ num_t,
    const float* __restrict__ den_t,
    float* __restrict__ out)          // [B][F(s)][F(e)][H]
{
    // XCD swizzle: xcd = blk&7 owns b in {2*xcd, 2*xcd+1} -> table slice
    // (0.74 MB) stays resident in that XCD's 4 MB L2.
    const int blk = blockIdx.x;        // 2048
    const int x = blk & 7;
    const int t = blk >> 3;            // 0..255
    const int b = 2 * x + (t >= 128);
    const int j = t & 127;
    const int sp = j >> 1;             // 0..63
    const int half = j & 1;
    const int tid = threadIdx.x;

    const float* nb = num_t + (size_t)b * (FF + 1) * HH;
    const float* db = den_t + (size_t)b * (FF + 1) * HH;
    float* out_b = out + (size_t)b * (FF * FF * HH);

    // paired s values: total work per block is constant across the grid
    k2_row_half(nb, db, out_b, sp, tid, half);
    k2_row_half(nb, db, out_b, 127 - sp, tid, half);
}

extern "C" void kernel_launch(void* const* d_in, const int* in_sizes, int n_in,
                              void* d_out, int out_size, void* d_ws, size_t ws_size,
                              hipStream_t stream) {
    const float* note = (const float*)d_in[0];
    const float* hv   = (const float*)d_in[1];
    const float* W0   = (const float*)d_in[2];
    const float* b0   = (const float*)d_in[3];
    const float* W1   = (const float*)d_in[4];
    const float* b1   = (const float*)d_in[5];
    const float* Wc   = (const float*)d_in[6];
    const float* bc   = (const float*)d_in[7];
    float* out = (float*)d_out;

    float* num_t = (float*)d_ws;
    float* den_t = num_t + TABLE_ELEMS;

    seg_k1<<<144, 256, 0, stream>>>(note, hv, W0, b0, W1, b1, Wc, bc, num_t, den_t);
    seg_k2<<<BB * FF, 256, 0, stream>>>(num_t, den_t, out);
}